// Round 5
// baseline (459.118 us; speedup 1.0000x reference)
//
#include <hip/hip_runtime.h>
#include <hip/hip_cooperative_groups.h>
#include <math.h>
#include <stdint.h>

namespace cg = cooperative_groups;

#define HW 512
#define IMG (HW*HW)
#define MLOG32f 3.4657359027997265f

// strict unfused fp32 to match reference per-op rounding (bin/threshold knife-edge)
__device__ __forceinline__ float grayf(float r, float g, float b) {
    float t = __fadd_rn(__fadd_rn(__fmul_rn(0.299f, r), __fmul_rn(0.587f, g)), __fmul_rn(0.114f, b));
    float s = __fmul_rn(0.5f, __fadd_rn(t, 1.0f));
    return fminf(fmaxf(s, 0.0f), 1.0f);
}

__device__ __forceinline__ float softplusf(float x) {
    return fmaxf(x, 0.0f) + log1pf(expf(-fabsf(x)));
}

__device__ __forceinline__ float frcp(float x)  { return __builtin_amdgcn_rcpf(x); }
__device__ __forceinline__ float frsq(float x)  { return __builtin_amdgcn_rsqf(x); }
__device__ __forceinline__ float flog1p(float x){ return __logf(1.0f + x); }

__device__ __forceinline__ uint64_t kmask(int lo, int hi) {
    return (1ull << hi) - (1ull << lo);
}

// ======================= single persistent cooperative kernel =======================
__global__ void __launch_bounds__(256, 4)
k_mega(const float* __restrict__ img, float* __restrict__ gray, int* __restrict__ hist,
       uint32_t* __restrict__ pn, float* __restrict__ zmap, float* __restrict__ nucf,
       float* __restrict__ Eout, float* __restrict__ Aout,
       const float* __restrict__ cal_a, const float* __restrict__ cal_b,
       const float* __restrict__ alpha_logits, const float* __restrict__ tau_p,
       float* __restrict__ expsum, int B) {
    cg::grid_group grid = cg::this_grid();

    __shared__ __align__(16) char smem[30912];
    __shared__ uint64_t nrow[50], ehr[50], dilh[50], bnd[36], cell[40];
    float* gt  = (float*)smem;             // 42*43 floats
    float* st  = (float*)(smem + 7232);    // 40*41
    float* ct  = (float*)(smem + 13792);   // 40*41
    float* rs0 = (float*)(smem + 20352);   // 40*33
    float* rs1 = (float*)(smem + 25632);   // 40*33
    int* rs_n = (int*)smem;                // 40*32 (aliases gt; float tiles dead by then)
    int* rs_c = (int*)(smem + 5120);
    int* rs_b = (int*)(smem + 10240);
    float* red = (float*)(smem + 16384);   // 4 floats (aliases ct tail, dead by then)
    uint64_t* s0m = (uint64_t*)smem;       // morph buffers (phase 3 only)
    uint64_t* s1m = s0m + 40;

    int tid = threadIdx.x;
    int lane = tid & 63, wv = tid >> 6;
    int nChunks = B * 64;                  // 4096 px per chunk
    int nTiles  = B * 256;                 // 32x32 px per tile

    // ---- scalar constants (redundant per thread; exact same op sequence as before) ----
    float w0f, w1f, w2f, w3f, bias, ntau;
    {
        float al[4];
        float m = -1e30f;
        #pragma unroll
        for (int c = 0; c < 4; c++) { al[c] = alpha_logits[c]; m = fmaxf(m, al[c]); }
        float e[4]; float s = 0.0f;
        #pragma unroll
        for (int c = 0; c < 4; c++) { e[c] = expf(al[c] - m); s += e[c]; }
        float w[4]; bias = 0.0f;
        #pragma unroll
        for (int c = 0; c < 4; c++) {
            float alpha = e[c] / s;
            w[c] = alpha * softplusf(cal_a[c]);
            bias += alpha * cal_b[c];
        }
        w0f = w[0]; w1f = w[1]; w2f = w[2]; w3f = w[3];
        float tau = 0.2f + softplusf(tau_p[0]);
        ntau = -1.0f / tau;
    }

    // =================== phase 1: gray + ballot histogram ===================
    for (int ch = blockIdx.x; ch < nChunks; ch += gridDim.x) {
        int b = ch >> 6;
        int f4base = (ch & 63) * 1024;     // 4096 px = 1024 float4
        const float4* rp = (const float4*)(img + (size_t)b * 3 * IMG) + f4base;
        const float4* gp = (const float4*)(img + (size_t)b * 3 * IMG + IMG) + f4base;
        const float4* bp = (const float4*)(img + (size_t)b * 3 * IMG + 2 * IMG) + f4base;
        float4* op = (float4*)(gray + (size_t)b * IMG) + f4base;
        int bin = lane & 31;
        int cnt = 0;
        #pragma unroll
        for (int it = 0; it < 4; it++) {
            int i = it * 256 + tid;
            float4 r = rp[i], g = gp[i], bb = bp[i];
            float4 o;
            o.x = grayf(r.x, g.x, bb.x);
            o.y = grayf(r.y, g.y, bb.y);
            o.z = grayf(r.z, g.z, bb.z);
            o.w = grayf(r.w, g.w, bb.w);
            op[i] = o;
            int idx[4];
            idx[0] = min(max((int)(o.x * 32.0f), 0), 31);
            idx[1] = min(max((int)(o.y * 32.0f), 0), 31);
            idx[2] = min(max((int)(o.z * 32.0f), 0), 31);
            idx[3] = min(max((int)(o.w * 32.0f), 0), 31);
            #pragma unroll
            for (int e = 0; e < 4; e++) {
                int v = idx[e];
                unsigned long long m0 = __ballot((v & 1)  != 0);
                unsigned long long m1 = __ballot((v & 2)  != 0);
                unsigned long long m2 = __ballot((v & 4)  != 0);
                unsigned long long m3 = __ballot((v & 8)  != 0);
                unsigned long long m4 = __ballot((v & 16) != 0);
                unsigned long long mm = (bin & 1)  ? m0 : ~m0;
                mm &= (bin & 2)  ? m1 : ~m1;
                mm &= (bin & 4)  ? m2 : ~m2;
                mm &= (bin & 8)  ? m3 : ~m3;
                mm &= (bin & 16) ? m4 : ~m4;
                cnt += __popcll(mm);
            }
        }
        if (lane < 32) atomicAdd(&hist[b * 32 + bin], cnt);
    }
    grid.sync();

    // =================== phase 3: otsu + threshold + bitwise morphology ===================
    for (int tile = blockIdx.x; tile < nTiles; tile += gridDim.x) {
        int b = tile >> 8, ti = tile & 255;
        int y0 = (ti >> 4) << 5, x0 = (ti & 15) << 5;
        int w0 = x0 >> 5;
        // --- array-free Otsu (accumulation order identical to omega/mu version) ---
        const int* h = hist + b * 32;
        float mu_t = 0.0f;
        #pragma unroll
        for (int k = 0; k < 32; k++) {
            float pk = (float)h[k] * (1.0f / 262144.0f);
            float xs = (float)((double)k / 31.0);
            mu_t += pk * xs;
        }
        float co = 0.0f, cm = 0.0f, best = -1e30f; int kb = 0;
        #pragma unroll
        for (int k = 0; k < 32; k++) {
            float pk = (float)h[k] * (1.0f / 262144.0f);
            float xs = (float)((double)k / 31.0);
            co += pk; cm += pk * xs;
            float t = mu_t * co - cm;
            float sb = (t * t) / (co * (1.0f - co) + 1e-8f);
            if (sb > best) { best = sb; kb = k; }   // first-max
        }
        float thrv = (float)kb * 0.03125f;

        const float* gb = gray + (size_t)b * IMG;
        // --- threshold -> 40-bit rows via ballot (bit k <-> x0-4+k) ---
        for (int r = wv; r < 40; r += 4) {
            int gy = y0 - 4 + r, gx = x0 - 4 + lane;
            bool pred = false;
            if (lane < 40 && (unsigned)gy < (unsigned)HW && (unsigned)gx < (unsigned)HW)
                pred = gb[gy * HW + gx] <= thrv;
            unsigned long long m = __ballot(pred);
            if (lane == 0) s0m[r] = m;          // OOB bits already 0
        }
        __syncthreads();
        int xlo = (x0 == 0) ? 4 : 0;
        int xhi = (x0 == 480) ? 36 : 40;
        uint64_t mwin = kmask(xlo, xhi);
        if (tid >= 1 && tid < 39) {
            uint64_t e = ~0ull;
            for (int dq = -1; dq <= 1; dq++) {
                int q = tid + dq;
                int y = y0 - 4 + q;
                uint64_t m = ((unsigned)y < (unsigned)HW) ? mwin : 0;
                uint64_t v = s0m[q] | ~m;
                e &= v & (v << 1) & (v >> 1);
            }
            s1m[tid] = e;
        }
        __syncthreads();
        if (tid >= 2 && tid < 38) {
            uint64_t d = 0;
            uint64_t me = kmask(1, 39);
            for (int dq = -1; dq <= 1; dq++) {
                int q = tid + dq;
                int y = y0 - 4 + q;
                uint64_t m = ((unsigned)y < (unsigned)HW) ? (mwin & me) : 0;
                uint64_t v = s1m[q] & m;
                d |= v | (v << 1) | (v >> 1);
            }
            s0m[tid] = d;
        }
        __syncthreads();
        if (tid >= 3 && tid < 37) {
            uint64_t d = 0;
            uint64_t me = kmask(2, 38);
            for (int dq = -1; dq <= 1; dq++) {
                int q = tid + dq;
                int y = y0 - 4 + q;
                uint64_t m = ((unsigned)y < (unsigned)HW) ? (mwin & me) : 0;
                uint64_t v = s0m[q] & m;
                d |= v | (v << 1) | (v >> 1);
            }
            s1m[tid] = d;
        }
        __syncthreads();
        if (tid >= 4 && tid < 36) {
            uint64_t e = ~0ull;
            uint64_t me = kmask(3, 37);
            for (int dq = -1; dq <= 1; dq++) {
                int q = tid + dq;
                int y = y0 - 4 + q;
                uint64_t m = ((unsigned)y < (unsigned)HW) ? (mwin & me) : 0;
                uint64_t v = s1m[q] | ~m;
                e &= v & (v << 1) & (v >> 1);
            }
            s0m[tid] = e;
        }
        __syncthreads();
        if (tid < 32) {
            int y = y0 + tid;
            pn[(size_t)b * 8192 + y * 16 + w0] = (uint32_t)(s0m[tid + 4] >> 4);
        }
        __syncthreads();
    }
    grid.sync();

    // =================== phase 4: fused concept maps + E + expsum ===================
    int p = tid & 31, py0 = (tid >> 5) << 2;
    for (int tile = blockIdx.x; tile < nTiles; tile += gridDim.x) {
        int b = tile >> 8, ti = tile & 255;
        int y0 = (ti >> 4) << 5, x0 = (ti & 15) << 5;
        int w0 = x0 >> 5;
        const float* gb = gray + (size_t)b * IMG;
        const uint32_t* pb = pn + (size_t)b * 8192;
        int xlo = (x0 == 0) ? 9 : 0;
        int xhi = (x0 == 480) ? 41 : 50;
        uint64_t mwin = kmask(xlo, xhi);

        for (int i = tid; i < 42 * 42; i += 256) {
            int ly = i / 42, lx = i % 42;
            int gy = y0 + ly - 5, gx = x0 + lx - 5;
            gt[ly * 43 + lx] = (gy >= 0 && gy < HW && gx >= 0 && gx < HW) ? gb[gy * HW + gx] : 0.0f;
        }
        if (tid < 50) {
            int y = y0 - 9 + tid;
            uint64_t v = 0;
            if ((unsigned)y < (unsigned)HW) {
                const uint32_t* rowp = pb + y * 16;
                uint64_t wm = (w0 > 0)  ? rowp[w0 - 1] : 0;
                uint64_t wc = rowp[w0];
                uint64_t wp = (w0 < 15) ? rowp[w0 + 1] : 0;
                v = ((wm >> 23) | (wc << 9) | (wp << 41)) & kmask(0, 50);
            }
            nrow[tid] = v;
        }
        __syncthreads();

        if (tid < 50) {
            uint64_t v = nrow[tid];
            uint64_t d = v | (v << 1) | (v >> 1);
            d = d | (d << 2) | (d >> 2);
            d = d | (d << 2) | (d >> 2);
            dilh[tid] = d;
        }
        if (tid >= 6 && tid < 44) {
            int y = y0 - 9 + tid;
            uint64_t m = ((unsigned)y < (unsigned)HW) ? mwin : 0;
            uint64_t v = nrow[tid] | ~m;
            ehr[tid] = v & (v << 1) & (v >> 1);
        }
        for (int i = tid; i < 1600; i += 256) {
            int ly = i / 40, lx = i % 40;
            int gy = y0 + ly - 4, gx = x0 + lx - 4;
            float s = 0.0f, c = 0.0f;
            if (gy >= 0 && gy < HW && gx >= 0 && gx < HW) {
                float a00 = gt[ly * 43 + lx],       a01 = gt[ly * 43 + lx + 1],       a02 = gt[ly * 43 + lx + 2];
                float a10 = gt[(ly + 1) * 43 + lx],                                   a12 = gt[(ly + 1) * 43 + lx + 2];
                float a20 = gt[(ly + 2) * 43 + lx], a21 = gt[(ly + 2) * 43 + lx + 1], a22 = gt[(ly + 2) * 43 + lx + 2];
                float gxv = (a00 - a02) + 2.0f * (a10 - a12) + (a20 - a22);
                float gyv = (a00 + 2.0f * a01 + a02) - (a20 + 2.0f * a21 + a22);
                float r2 = gxv * gxv + gyv * gyv;
                if (r2 > 0.0f) { float ir = frsq(r2); s = gyv * ir; c = gxv * ir; }
                else { s = 0.0f; c = 1.0f; }
            }
            st[ly * 41 + lx] = s; ct[ly * 41 + lx] = c;
        }
        __syncthreads();

        if (tid < 36) {
            int r = tid + 7;
            uint64_t er = ehr[r - 1] & ehr[r] & ehr[r + 1];
            bnd[tid] = nrow[r] & ~er;
        }
        if (tid < 40) {
            int r = tid + 5;
            int y = y0 - 4 + tid;
            uint64_t c = 0;
            for (int d = -5; d <= 5; d++) c |= dilh[r + d];
            uint64_t m = ((unsigned)y < (unsigned)HW) ? mwin : 0;
            cell[tid] = c & m;
        }
        for (int i = tid; i < 320; i += 256) {
            int ly = i >> 3, c0 = (i & 7) << 2;
            int base = ly * 41 + c0;
            float sa[12], ca[12];
            #pragma unroll
            for (int j = 0; j < 12; j++) { sa[j] = st[base + j]; ca[j] = ct[base + j]; }
            float ss = sa[0]+sa[1]+sa[2]+sa[3]+sa[4]+sa[5]+sa[6]+sa[7]+sa[8];
            float cs = ca[0]+ca[1]+ca[2]+ca[3]+ca[4]+ca[5]+ca[6]+ca[7]+ca[8];
            int ob = ly * 33 + c0;
            rs0[ob] = ss; rs1[ob] = cs;
            #pragma unroll
            for (int q = 1; q < 4; q++) {
                ss += sa[8 + q] - sa[q - 1];
                cs += ca[8 + q] - ca[q - 1];
                rs0[ob + q] = ss; rs1[ob + q] = cs;
            }
        }
        __syncthreads();

        int gx = x0 + p;
        float cntx = (float)(min(gx + 4, HW - 1) - max(gx - 4, 0) + 1);
        float z1v[4], z3v[4];
        {
            float s[12], c[12];
            #pragma unroll
            for (int j = 0; j < 12; j++) { s[j] = rs0[(py0 + j) * 33 + p]; c[j] = rs1[(py0 + j) * 33 + p]; }
            float ss = s[0]+s[1]+s[2]+s[3]+s[4]+s[5]+s[6]+s[7]+s[8];
            float cs = c[0]+c[1]+c[2]+c[3]+c[4]+c[5]+c[6]+c[7]+c[8];
            #pragma unroll
            for (int q = 0; q < 4; q++) {
                int gy = y0 + py0 + q;
                float cnty = (float)(min(gy + 4, HW - 1) - max(gy - 4, 0) + 1);
                float iden = frcp(cnty * cntx + 1e-6f);
                float ms = ss * iden, mc = cs * iden;
                z1v[q] = 1.0f - sqrtf(ms * ms + mc * mc + 1e-6f);
                if (q < 3) { ss += s[9 + q] - s[q]; cs += c[9 + q] - c[q]; }
            }
        }
        __syncthreads();

        for (int i = tid; i < 320; i += 256) {
            int ly = i >> 3, c0 = (i & 7) << 2;
            int base = (ly + 1) * 43 + c0 + 1;
            float v[12];
            #pragma unroll
            for (int j = 0; j < 12; j++) v[j] = gt[base + j];
            float gs = v[0]+v[1]+v[2]+v[3]+v[4]+v[5]+v[6]+v[7]+v[8];
            float g2 = v[0]*v[0]+v[1]*v[1]+v[2]*v[2]+v[3]*v[3]+v[4]*v[4]+v[5]*v[5]+v[6]*v[6]+v[7]*v[7]+v[8]*v[8];
            int ob = ly * 33 + c0;
            rs0[ob] = gs; rs1[ob] = g2;
            #pragma unroll
            for (int q = 1; q < 4; q++) {
                gs += v[8 + q] - v[q - 1];
                g2 += v[8 + q] * v[8 + q] - v[q - 1] * v[q - 1];
                rs0[ob + q] = gs; rs1[ob + q] = g2;
            }
        }
        __syncthreads();

        {
            float s[12], c[12];
            #pragma unroll
            for (int j = 0; j < 12; j++) { s[j] = rs0[(py0 + j) * 33 + p]; c[j] = rs1[(py0 + j) * 33 + p]; }
            float gs = s[0]+s[1]+s[2]+s[3]+s[4]+s[5]+s[6]+s[7]+s[8];
            float g2 = c[0]+c[1]+c[2]+c[3]+c[4]+c[5]+c[6]+c[7]+c[8];
            #pragma unroll
            for (int q = 0; q < 4; q++) {
                int gy = y0 + py0 + q;
                float cnty = (float)(min(gy + 4, HW - 1) - max(gy - 4, 0) + 1);
                float iden = frcp(cnty * cntx + 1e-6f);
                float g1 = gs * iden, gq = g2 * iden;
                z3v[q] = flog1p(fmaxf(gq - g1 * g1, 0.0f));
                if (q < 3) { gs += s[9 + q] - s[q]; g2 += c[9 + q] - c[q]; }
            }
        }
        __syncthreads();   // float LDS dead; int arrays may alias

        for (int i = tid; i < 40 * 32; i += 256) {
            int rr = i >> 5, pp = i & 31;
            rs_n[rr * 32 + pp] = __popcll((nrow[rr + 5] >> (pp + 5)) & 0x1FFull);
            rs_c[rr * 32 + pp] = __popcll((cell[rr]     >> (pp + 5)) & 0x1FFull);
        }
        for (int i = tid; i < 36 * 32; i += 256) {
            int rr = i >> 5, pp = i & 31;
            rs_b[rr * 32 + pp] = __popcll((bnd[rr] >> (pp + 7)) & 0x1Full);
        }
        __syncthreads();

        float* z0p = zmap + ((size_t)b * 4 + 0) * IMG;
        float* z1p = zmap + ((size_t)b * 4 + 1) * IMG;
        float* z2p = zmap + ((size_t)b * 4 + 2) * IMG;
        float* z3p = zmap + ((size_t)b * 4 + 3) * IMG;
        float* Ep  = Eout + (size_t)b * IMG;
        float* np  = nucf + (size_t)b * IMG;
        float acc = 0.0f;
        {
            int nn[12], cc[12], bb8[8];
            #pragma unroll
            for (int j = 0; j < 12; j++) { nn[j] = rs_n[(py0 + j) * 32 + p]; cc[j] = rs_c[(py0 + j) * 32 + p]; }
            #pragma unroll
            for (int j = 0; j < 8; j++) bb8[j] = rs_b[(py0 + j) * 32 + p];
            int An = nn[0]+nn[1]+nn[2]+nn[3]+nn[4]+nn[5]+nn[6]+nn[7]+nn[8];
            int Ac = cc[0]+cc[1]+cc[2]+cc[3]+cc[4]+cc[5]+cc[6]+cc[7]+cc[8];
            int db = bb8[0]+bb8[1]+bb8[2]+bb8[3]+bb8[4];
            int kk = p + 9;
            #pragma unroll
            for (int q = 0; q < 4; q++) {
                int py = py0 + q;
                int r = py + 9;
                uint64_t rowc = nrow[r];
                int cbit = (int)((rowc >> kk) & 1);
                int nb4  = (int)((nrow[r - 1] >> kk) & 1) + (int)((nrow[r + 1] >> kk) & 1)
                         + (int)((rowc >> (kk - 1)) & 1) + (int)((rowc >> (kk + 1)) & 1);
                int lap = nb4 - 4 * cbit; lap = lap < 0 ? -lap : lap;
                int bc  = (int)((bnd[py + 2] >> kk) & 1);
                float rough = (float)(lap * bc) * frcp((float)db + 1e-6f);
                float z2 = (float)An * frcp(fmaxf((float)(Ac - An), 1.0f));
                float z0s = flog1p(fmaxf(rough, 0.0f));
                float z1s = fminf(fmaxf(z1v[q], 0.0f), 1.0f);
                float z2s = flog1p(fmaxf(z2, 0.0f));
                float z3s = fminf(fmaxf(z3v[q], 0.0f), MLOG32f);
                float E = w0f * z0s + w1f * z1s + w2f * z2s + w3f * z3s + bias;
                int gy = y0 + py;
                size_t o = (size_t)gy * HW + x0 + p;
                z0p[o] = rough;
                z1p[o] = z1v[q];
                z2p[o] = z2;
                z3p[o] = z3v[q];
                Ep[o]  = E;
                np[o]  = (float)cbit;
                acc += __expf(E * ntau);
                if (q < 3) {
                    An += nn[9 + q] - nn[q];
                    Ac += cc[9 + q] - cc[q];
                    db += bb8[5 + q] - bb8[q];
                }
            }
        }
        for (int off = 32; off > 0; off >>= 1) acc += __shfl_down(acc, off, 64);
        if (lane == 0) red[wv] = acc;
        __syncthreads();
        if (tid == 0) atomicAdd(&expsum[b], red[0] + red[1] + red[2] + red[3]);
        __syncthreads();
    }
    grid.sync();

    // =================== phase 5: A = exp(-E/tau) / S ===================
    int nF4 = B * (IMG / 4);
    for (int j = blockIdx.x * 256 + tid; j < nF4; j += gridDim.x * 256) {
        int b = j >> 16;                       // IMG/4 = 65536
        float invS = 1.0f / expsum[b];
        float4 e = ((const float4*)Eout)[j];
        float4 o;
        o.x = __expf(e.x * ntau) * invS;
        o.y = __expf(e.y * ntau) * invS;
        o.z = __expf(e.z * ntau) * invS;
        o.w = __expf(e.w * ntau) * invS;
        ((float4*)Aout)[j] = o;
    }
}

extern "C" void kernel_launch(void* const* d_in, const int* in_sizes, int n_in,
                              void* d_out, int out_size, void* d_ws, size_t ws_size,
                              hipStream_t stream) {
    const float* img   = (const float*)d_in[0];
    const float* cal_a = (const float*)d_in[1];
    const float* cal_b = (const float*)d_in[2];
    const float* alpha = (const float*)d_in[3];
    const float* tau_p = (const float*)d_in[4];
    int B = in_sizes[0] / (3 * IMG);

    float* out  = (float*)d_out;
    float* A    = out;                          // (B,1,H,W)
    float* zmap = out + (size_t)B * IMG;        // (B,4,H,W)
    float* nuc  = out + (size_t)B * IMG * 5;    // (B,1,H,W)
    float* E    = out + (size_t)B * IMG * 6;    // (B,1,H,W)
    float* gray = A;                            // A region doubles as gray scratch (A written last)

    // ws: hist(B*32 int) | expsum(B float) | pad | packedN(B*8192 u32)
    int*      hist    = (int*)d_ws;
    float*    expsum  = (float*)d_ws + B * 32;
    uint32_t* packedN = (uint32_t*)((char*)d_ws + 4096);

    hipMemsetAsync(d_ws, 0, (size_t)(B * 32 + B) * 4, stream);

    int maxB = 0;
    hipOccupancyMaxActiveBlocksPerMultiprocessor(&maxB, k_mega, 256, 0);
    if (maxB < 1) maxB = 1;
    int G = maxB * 256;                         // 256 CUs on MI355X
    if (G > B * 64) G = B * 64;                 // no more blocks than chunks (1024)

    void* args[] = {(void*)&img, (void*)&gray, (void*)&hist, (void*)&packedN,
                    (void*)&zmap, (void*)&nuc, (void*)&E, (void*)&A,
                    (void*)&cal_a, (void*)&cal_b, (void*)&alpha, (void*)&tau_p,
                    (void*)&expsum, (void*)&B};
    hipLaunchCooperativeKernel((void*)k_mega, dim3(G), dim3(256), args, 0, stream);
}